// Round 9
// baseline (242.708 us; speedup 1.0000x reference)
//
#include <hip/hip_runtime.h>
#include <math.h>

// LogPolar resample: data [32,3,512,512] f32 -> out [32,3,512,512] f32.
// R4: 8 XCD-pinned image chunks -> FETCH 327->50MB, 173us.
// R6: float2 row-pair gathers + 8x8 wave tiles -> 113us.
// R8: nt stores regressed WRITE 116->136MB; "pipeline" was defeated by the
// scheduler (VGPR stayed 32 => loads sunk to uses, MLP never tested).
// R9: (a) plain stores again; (b) sched_barrier(0) between a 24-load gather
// phase and the compute/store phase — compiler cannot sink loads across it,
// so all 24 float2 results stay live (expect VGPR ~80, true MLP ~24).

constexpr int H_IN  = 512;
constexpr int W_IN  = 512;
constexpr int H_OUT = 512;
constexpr int W_OUT = 512;
constexpr int BC    = 32 * 3;          // batch * channels
constexpr int IMG   = H_IN * W_IN;     // elements per image plane
constexpr int NCHUNK = 8;              // = #XCDs
constexpr int IPC   = BC / NCHUNK;     // 12 images per chunk

__device__ __forceinline__ float2 ld2(const float* p) {
    // well-defined unaligned 8B load; lowers to global_load_dwordx2 align 4
    float2 v;
    __builtin_memcpy(&v, p, sizeof(v));
    return v;
}

__global__ __launch_bounds__(256) void logpolar_kernel(
    const float* __restrict__ data, float* __restrict__ out)
{
    // chunk pinned to XCD: consecutive blocks round-robin the 8 XCDs.
    const int chunk = blockIdx.x & (NCHUNK - 1);
    const int tile  = blockIdx.x >> 3;            // 0..1023: 32x32 tiles of 16x16 px
    const int tile_i = (tile >> 5) << 4;
    const int tile_j = (tile & 31) << 4;

    // 8x8 px per wave; block = 2x2 waves = 16x16 px tile.
    const int t = threadIdx.x;
    const int w = t >> 6;                          // wave 0..3
    const int l = t & 63;                          // lane
    const int i = tile_i + ((w >> 1) << 3) + (l >> 3);   // theta row
    const int j = tile_j + ((w & 1) << 3) + (l & 7);     // r col
    const int pix = (i << 9) | j;

    // max_r = np.float32(log(norm([512,512])/2 * 2.0)) — f64 value, exact cast.
    const float max_r = (float)6.584898215319481;

    // Mirror reference f32 op order: (theta*2*pi)/H_OUT ; (r*max_r)/W_OUT
    const float theta  = ((float)(2 * i) * 3.14159274101257324f) / (float)H_OUT;
    const float radius = expf(((float)j * max_r) / (float)W_OUT);
    const float X = 256.0f + radius * cosf(theta);   // center_x + X0
    const float Y = 256.0f - radius * sinf(theta);   // center_y - Y0

    const float* p = data + (size_t)chunk * IPC * IMG;
    float*       q = out  + (size_t)chunk * IPC * IMG + pix;

    const bool in_bounds =
        (X >= 0.0f) && (X < (float)H_IN) && (Y >= 0.0f) && (Y < (float)W_IN);

    if (!in_bounds) {
        // mask == 0: reference multiplies the blend by 0 (inputs finite) -> exact 0.
        #pragma unroll
        for (int bc = 0; bc < IPC; ++bc) q[bc * IMG] = 0.0f;
        return;
    }

    // trunc-toward-zero (X,Y >= 0 here); in-bounds => within [0,511].
    const int y_down = (int)Y;
    const int x_down = (int)X;
    const int y_up = min(y_down + 1, H_IN - 1);
    const int x_up = min(x_down + 1, W_IN - 1);

    const float yd = Y - (float)y_down;
    const float yu = Y - (float)y_up;
    const float xd = X - (float)x_down;
    const float xu = X - (float)x_up;

    const float dd = yd * yd + xd * xd;
    const float du = yd * yd + xu * xu;
    const float ud = yu * yu + xd * xd;
    const float uu = yu * yu + xu * xu;
    const float total = ((dd + du) + ud) + uu;

    const float wdd = dd / total;
    const float wdu = du / total;
    const float wud = ud / total;
    const float wuu = uu / total;

    const int o_d = y_down * W_IN + x_down;   // row y_down, cols x_down..x_down+1
    const int o_u = y_up   * W_IN + x_down;   // row y_up

    if (x_down < W_IN - 1) {
        // ---- gather phase: 24 float2 loads, all issued before any use ----
        float2 gd[IPC], gu[IPC];
        #pragma unroll
        for (int bc = 0; bc < IPC; ++bc) {
            gd[bc] = ld2(p + bc * IMG + o_d);   // g_dd, g_du
            gu[bc] = ld2(p + bc * IMG + o_u);   // g_ud, g_uu
        }
        // Hard fence: compiler may not sink loads below this point, so all
        // 24 results stay live in VGPRs -> ~24 loads in flight per thread.
        __builtin_amdgcn_sched_barrier(0);
        // ---- compute + store phase ----
        #pragma unroll
        for (int bc = 0; bc < IPC; ++bc) {
            q[bc * IMG] =
                ((wdd * gd[bc].x + wdu * gd[bc].y) + wud * gu[bc].x) + wuu * gu[bc].y;
        }
    } else {
        // x_down == 511 -> x_up clamps to 511: both column taps alias
        #pragma unroll
        for (int bc = 0; bc < IPC; ++bc) {
            const float* pp = p + bc * IMG;
            const float ga = pp[o_d];
            const float gb = pp[o_u];
            q[bc * IMG] = ((wdd * ga + wdu * ga) + wud * gb) + wuu * gb;
        }
    }
}

extern "C" void kernel_launch(void* const* d_in, const int* in_sizes, int n_in,
                              void* d_out, int out_size, void* d_ws, size_t ws_size,
                              hipStream_t stream)
{
    const float* data = (const float*)d_in[0];
    float* out = (float*)d_out;

    const int threads = 256;                       // 16x16 px tile per block
    const int blocks = (H_OUT / 16) * (W_OUT / 16) * NCHUNK;  // 1024 * 8 = 8192
    logpolar_kernel<<<blocks, threads, 0, stream>>>(data, out);
}